// Round 5
// baseline (141.199 us; speedup 1.0000x reference)
//
#include <hip/hip_runtime.h>
#include <math.h>

typedef __attribute__((ext_vector_type(8))) short short8;
typedef __attribute__((ext_vector_type(4))) float f32x4;

#define BB 8
#define CC 256
#define OO 256
#define HH 56
#define WW 56
#define HWH 3136
#define RED 16

__device__ inline unsigned short f2bf(float f) {
    unsigned u = __builtin_bit_cast(unsigned, f);
    u = (u + 0x7fffu + ((u >> 16) & 1u)) >> 16;
    return (unsigned short)u;
}
__device__ inline float bf2f(unsigned short h) {
    return __builtin_bit_cast(float, ((unsigned)h) << 16);
}
__device__ inline unsigned cvtpk(float lo, float hi) {
    unsigned r;
    asm("v_cvt_pk_bf16_f32 %0, %1, %2" : "=v"(r) : "v"(lo), "v"(hi));
    return r;
}
__device__ inline float fast_tanh(float x) {
    float e = __expf(2.0f * x);
    return 1.0f - 2.0f / (e + 1.0f);
}
__device__ inline void gl2lds16(const void* g, void* l) {
    __builtin_amdgcn_global_load_lds((const __attribute__((address_space(1))) unsigned int*)g,
                                     (__attribute__((address_space(3))) unsigned int*)l, 16, 0, 0);
}

// ---------------- SE: mean over H,W ----------------
__global__ __launch_bounds__(256) void se_mean(const float* __restrict__ x, float* __restrict__ y) {
    int bc = blockIdx.x;
    const float4* p = (const float4*)(x + (size_t)bc * HWH);
    float sum = 0.f;
    for (int i = threadIdx.x; i < HWH / 4; i += 256) {
        float4 v = p[i];
        sum += v.x + v.y + v.z + v.w;
    }
    __shared__ float sm[4];
    for (int off = 32; off > 0; off >>= 1) sum += __shfl_down(sum, off);
    if ((threadIdx.x & 63) == 0) sm[threadIdx.x >> 6] = sum;
    __syncthreads();
    if (threadIdx.x == 0) y[bc] = (sm[0] + sm[1] + sm[2] + sm[3]) * (1.0f / HWH);
}

// ---------------- SE: fc1->relu->fc2->sigmoid ----------------
__global__ __launch_bounds__(256) void se_fc(const float* __restrict__ y, const float* __restrict__ fc1,
                                             const float* __restrict__ fc2, float* __restrict__ s) {
    __shared__ float hbuf[BB * RED];
    int t = threadIdx.x;
    if (t < BB * RED) {
        int b = t / RED, r = t % RED;
        float acc = 0.f;
        for (int c = 0; c < CC; ++c) acc += y[b * CC + c] * fc1[r * CC + c];
        hbuf[t] = fmaxf(acc, 0.f);
    }
    __syncthreads();
    for (int i = t; i < BB * CC; i += 256) {
        int b = i / CC, c = i % CC;
        float acc = 0.f;
        #pragma unroll
        for (int r = 0; r < RED; ++r) acc += hbuf[b * RED + r] * fc2[c * RED + r];
        s[i] = 1.0f / (1.0f + expf(-acc));
    }
}

// ---------------- NCHW f32 -> NHWC bf16, scaled by s ----------------
__global__ __launch_bounds__(256) void prep_xt(const float* __restrict__ x, const float* __restrict__ s,
                                               unsigned short* __restrict__ x_t) {
    __shared__ float t[64][65];
    int blk = blockIdx.x;
    int ct = blk & 3;
    int hwt = (blk >> 2) % 49;
    int b = blk / (4 * 49);
    int c0 = ct * 64, hw0 = hwt * 64;
    int tid = threadIdx.x;
    const float* xb = x + ((size_t)(b * CC + c0)) * HWH + hw0;
    #pragma unroll
    for (int it = 0; it < 16; ++it) {
        int idx = it * 256 + tid;
        int c = idx >> 6, px = idx & 63;
        t[c][px] = xb[(size_t)c * HWH + px];
    }
    __syncthreads();
    unsigned short* xo = x_t + ((size_t)(b * HWH + hw0)) * CC + c0;
    #pragma unroll
    for (int it = 0; it < 16; ++it) {
        int idx = it * 256 + tid;
        int px = idx >> 6, c = idx & 63;
        xo[(size_t)px * CC + c] = f2bf(t[c][px] * s[b * CC + c0 + c]);
    }
}

// ---------------- deform weights -> per-MFMA-fragment contiguous layout ----------------
// idx = ((t*8 + og)*4 + f)*64 + lane ; f = n*2+kh ; each entry 8 shorts
// value = w_conv[o][c][kk], o = og*32 + n*16 + (lane&15), c = (t&3)*64 + kh*32 + (lane>>4)*8 + e, kk = t>>2
__global__ __launch_bounds__(256) void prep_wcf(const float* __restrict__ w_conv, unsigned short* __restrict__ wbf) {
    int idx = blockIdx.x * 256 + threadIdx.x;   // 73728
    int lane = idx & 63;
    int f = (idx >> 6) & 3;
    int og = (idx >> 8) & 7;
    int t = idx >> 11;
    int kk = t >> 2, cc = t & 3;
    int n = f >> 1, kh = f & 1;
    int o = og * 32 + n * 16 + (lane & 15);
    int cb2 = cc * 64 + kh * 32 + ((lane >> 4) << 3);
    short8 r;
    #pragma unroll
    for (int e = 0; e < 8; ++e) r[e] = (short)f2bf(w_conv[(size_t)(o * 256 + cb2 + e) * 9 + kk]);
    *(short8*)(wbf + (size_t)idx * 8) = r;
}

// ---------------- offset weights -> 36 pre-swizzled 4KB tiles (o padded to 32) ----------------
__global__ __launch_bounds__(256) void prep_wo(const float* __restrict__ w_off, unsigned short* __restrict__ wbo) {
    int idx = blockIdx.x * 256 + threadIdx.x;    // 36*32*8 = 9216
    int g = idx & 7;
    int o = (idx >> 3) & 31;
    int t = idx >> 8;
    int kk = t >> 2, cc = t & 3;
    int dst = (((o * 128 + g * 16) ^ ((o & 7) << 4)) >> 1);
    short8 r;
    #pragma unroll
    for (int e = 0; e < 8; ++e) {
        int c = cc * 64 + g * 8 + e;
        r[e] = (o < 18) ? (short)f2bf(w_off[(size_t)(o * 256 + c) * 9 + kk]) : (short)0;
    }
    *(short8*)(wbo + (size_t)t * 2048 + dst) = r;
}

// ---------------- offset conv via MFMA: 784 blocks, 32px x 32o, 4 waves (2m x 2ksplit) ----------------
__global__ __launch_bounds__(256) void offset_mfma(const unsigned short* __restrict__ x_t,
                                                   const unsigned short* __restrict__ wbo,
                                                   const float* __restrict__ b_off,
                                                   float* __restrict__ offs) {
    __shared__ __align__(16) char As[4][4096];   // [q*2+buf]
    __shared__ __align__(16) char Bs[4][4096];
    __shared__ float red[128 * 8];
    int blk = blockIdx.x;
    blk = (blk & 7) * 98 + (blk >> 3);
    int b = blk / 98;
    int hw0 = (blk % 98) * 32;
    int tid = threadIdx.x;
    int lane = tid & 63, wv = tid >> 6;
    int ks = wv >> 1, m = wv & 1;
    int r0 = lane & 15, kb = (lane >> 4) << 4;
    int px = tid >> 3, c8 = tid & 7;
    int hwp = hw0 + px;
    int hp = hwp / 56, wp_ = hwp - hp * 56;
    int awoff = (px * 128 + c8 * 16) ^ ((px & 7) << 4);
    f32x4 zero = {0.f, 0.f, 0.f, 0.f};
    f32x4 acc[2] = {zero, zero};

    auto buildA = [&](int q, int r, int buf) {
        int t = q * 18 + r;
        int kk = t >> 2, cc = t & 3;
        int hh = hp + kk / 3 - 1, ww = wp_ + kk % 3 - 1;
        short8 v = {0, 0, 0, 0, 0, 0, 0, 0};
        if (hh >= 0 && hh < 56 && ww >= 0 && ww < 56)
            v = *(const short8*)(x_t + (((size_t)(b * HWH + hh * 56 + ww)) << 8) + cc * 64 + c8 * 8);
        *(short8*)(As[q * 2 + buf] + awoff) = v;
    };
    auto stageB = [&](int q, int r, int buf) {
        int t = q * 18 + r;
        gl2lds16(wbo + (size_t)t * 2048 + tid * 8, Bs[q * 2 + buf] + (tid >> 6) * 1024);
    };

    stageB(0, 0, 0); stageB(1, 0, 0);
    buildA(0, 0, 0); buildA(1, 0, 0);
    __syncthreads();

    #pragma unroll 2
    for (int r = 0; r < 18; ++r) {
        int cur = r & 1;
        if (r < 17) {
            stageB(0, r + 1, cur ^ 1); stageB(1, r + 1, cur ^ 1);
            buildA(0, r + 1, cur ^ 1); buildA(1, r + 1, cur ^ 1);
        }
        short8 a[2];
        #pragma unroll
        for (int kh = 0; kh < 2; ++kh) {
            int row = m * 16 + r0;
            int ao = (row * 128 + kh * 64 + kb) ^ ((row & 7) << 4);
            a[kh] = *(const short8*)(As[ks * 2 + cur] + ao);
        }
        #pragma unroll
        for (int n = 0; n < 2; ++n)
            #pragma unroll
            for (int kh = 0; kh < 2; ++kh) {
                int brow = n * 16 + r0;
                int bo = (brow * 128 + kh * 64 + kb) ^ ((brow & 7) << 4);
                short8 bv = *(const short8*)(Bs[ks * 2 + cur] + bo);
                acc[n] = __builtin_amdgcn_mfma_f32_16x16x32_bf16(a[kh], bv, acc[n], 0, 0, 0);
            }
        __syncthreads();
    }

    if (ks == 1) {
        #pragma unroll
        for (int n = 0; n < 2; ++n)
            *(f32x4*)&red[(m * 64 + lane) * 8 + n * 4] = acc[n];
    }
    __syncthreads();
    if (ks == 0) {
        #pragma unroll
        for (int n = 0; n < 2; ++n) {
            f32x4 o2 = *(const f32x4*)&red[(m * 64 + lane) * 8 + n * 4];
            acc[n] += o2;
            int o = n * 16 + r0;
            if (o < 18) {
                float bia = b_off[o];
                #pragma unroll
                for (int j = 0; j < 4; ++j)
                    offs[((size_t)(b * 18 + o)) * HWH + hw0 + m * 16 + ((lane >> 4) << 2) + j] = acc[n][j] + bia;
            }
        }
    }
}

// ---------------- precompute bilinear coords: bases (int4) + weights (float4) ----------------
__global__ __launch_bounds__(256) void coords_prep(const float* __restrict__ offs,
                                                   int4* __restrict__ ci, float4* __restrict__ cf) {
    int idx = blockIdx.x * 256 + threadIdx.x;    // 8*9*3136 = 225792
    int hw = idx % 3136;
    int t = idx / 3136;
    int kk = t % 9;
    int b = t / 9;
    int h = hw / 56, w = hw - h * 56;
    float dy = offs[((size_t)(b * 18 + kk * 2)) * HWH + hw];
    float dx = offs[((size_t)(b * 18 + kk * 2 + 1)) * HWH + hw];
    float ys = (float)(h - 1 + kk / 3) + dy;
    float xs = (float)(w - 1 + kk % 3) + dx;
    float y0f = floorf(ys), x0f = floorf(xs);
    float wy = ys - y0f, wx = xs - x0f;
    int y0 = (int)y0f, x0 = (int)x0f;
    int bi[4]; float wt[4];
    #pragma unroll
    for (int j = 0; j < 4; ++j) {
        int yj = y0 + (j >> 1), xj = x0 + (j & 1);
        bool val = yj >= 0 && yj < 56 && xj >= 0 && xj < 56;
        int yc = min(max(yj, 0), 55), xc = min(max(xj, 0), 55);
        wt[j] = val ? ((j >> 1) ? wy : 1.f - wy) * ((j & 1) ? wx : 1.f - wx) : 0.f;
        bi[j] = (b * HWH + yc * 56 + xc) << 8;
    }
    ci[idx] = make_int4(bi[0], bi[1], bi[2], bi[3]);
    cf[idx] = make_float4(wt[0], wt[1], wt[2], wt[3]);
}

// ---------------- deformable conv: 784 blocks x 512 thr, 32px x 256o, 8 o-waves ----------------
__global__ __launch_bounds__(512, 4) void deform_mfma(const unsigned short* __restrict__ x_t,
                                                      const int4* __restrict__ ci,
                                                      const float4* __restrict__ cf,
                                                      const unsigned short* __restrict__ wbf,
                                                      const float* __restrict__ b_conv,
                                                      float* __restrict__ out) {
    __shared__ __align__(16) char As[16384];     // 4 tiles x 4KB; pair p uses tiles {(p&1)*2, +1}
    int blk = blockIdx.x;
    blk = (blk & 7) * 98 + (blk >> 3);           // 784 = 8*98, bijective
    int b = blk / 98;
    int hw0 = (blk % 98) * 32;
    int tid = threadIdx.x;
    int lane = tid & 63, og = tid >> 6;
    int px = tid >> 4, c8 = tid & 15;            // A-build: 32px x 16 ch-groups of 8
    int r0 = lane & 15, kb = (lane >> 4) << 4;
    int cidxB = b * 9 * HWH + hw0 + px;
    int awoff = (px * 128 + (c8 & 7) * 16) ^ ((px & 7) << 4);
    const unsigned short* wbB = wbf + (size_t)(og * 4) * 512 + lane * 8;

    f32x4 zero = {0.f, 0.f, 0.f, 0.f};
    f32x4 acc[2][2];
    #pragma unroll
    for (int m = 0; m < 2; ++m)
        #pragma unroll
        for (int n = 0; n < 2; ++n) acc[m][n] = zero;

    // prologue: build pair 0 into tiles 0,1
    {
        int4 cb = ci[cidxB];
        float4 cw = cf[cidxB];
        int ch = c8 * 8;
        short8 v0 = *(const short8*)(x_t + cb.x + ch);
        short8 v1 = *(const short8*)(x_t + cb.y + ch);
        short8 v2 = *(const short8*)(x_t + cb.z + ch);
        short8 v3 = *(const short8*)(x_t + cb.w + ch);
        float f[8];
        #pragma unroll
        for (int e = 0; e < 8; ++e) {
            float fv = cw.x * bf2f((unsigned short)v0[e]);
            fv = fmaf(cw.y, bf2f((unsigned short)v1[e]), fv);
            fv = fmaf(cw.z, bf2f((unsigned short)v2[e]), fv);
            fv = fmaf(cw.w, bf2f((unsigned short)v3[e]), fv);
            f[e] = fv;
        }
        unsigned pk[4];
        #pragma unroll
        for (int q = 0; q < 4; ++q) pk[q] = cvtpk(f[q * 2], f[q * 2 + 1]);
        *(uint4*)(As + (c8 >> 3) * 4096 + awoff) = make_uint4(pk[0], pk[1], pk[2], pk[3]);
    }
    __syncthreads();

    #pragma unroll 2
    for (int p = 0; p < 18; ++p) {
        // ---- B fragments for pair p (2 chunks x 4 frags, contiguous 1KB each) ----
        const unsigned short* wp = wbB + (size_t)p * 32768;
        short8 bv[8];
        #pragma unroll
        for (int f = 0; f < 4; ++f) bv[f] = *(const short8*)(wp + f * 512);
        #pragma unroll
        for (int f = 0; f < 4; ++f) bv[4 + f] = *(const short8*)(wp + 16384 + f * 512);
        // ---- issue next-pair corner loads ----
        short8 cv0, cv1, cv2, cv3;
        float4 cwN;
        int tbn = 0;
        if (p < 17) {
            int pn = p + 1;
            int kk = pn >> 1;
            int4 cb = ci[cidxB + kk * HWH];
            cwN = cf[cidxB + kk * HWH];
            int ch = (pn & 1) * 128 + c8 * 8;
            cv0 = *(const short8*)(x_t + cb.x + ch);
            cv1 = *(const short8*)(x_t + cb.y + ch);
            cv2 = *(const short8*)(x_t + cb.z + ch);
            cv3 = *(const short8*)(x_t + cb.w + ch);
            tbn = ((pn & 1) << 1) | (c8 >> 3);
        }
        // ---- MFMA pair p ----
        #pragma unroll
        for (int q = 0; q < 2; ++q) {
            int tb = (p & 1) * 2 + q;
            short8 a[2][2];
            #pragma unroll
            for (int m = 0; m < 2; ++m)
                #pragma unroll
                for (int kh = 0; kh < 2; ++kh) {
                    int row = m * 16 + r0;
                    int ao = (row * 128 + kh * 64 + kb) ^ ((row & 7) << 4);
                    a[m][kh] = *(const short8*)(As + tb * 4096 + ao);
                }
            #pragma unroll
            for (int n = 0; n < 2; ++n)
                #pragma unroll
                for (int kh = 0; kh < 2; ++kh)
                    #pragma unroll
                    for (int m = 0; m < 2; ++m)
                        acc[m][n] = __builtin_amdgcn_mfma_f32_16x16x32_bf16(a[m][kh], bv[q * 4 + n * 2 + kh], acc[m][n], 0, 0, 0);
        }
        // ---- bilinear + LDS write for pair p+1 ----
        if (p < 17) {
            float f[8];
            #pragma unroll
            for (int e = 0; e < 8; ++e) {
                float fv = cwN.x * bf2f((unsigned short)cv0[e]);
                fv = fmaf(cwN.y, bf2f((unsigned short)cv1[e]), fv);
                fv = fmaf(cwN.z, bf2f((unsigned short)cv2[e]), fv);
                fv = fmaf(cwN.w, bf2f((unsigned short)cv3[e]), fv);
                f[e] = fv;
            }
            unsigned pk[4];
            #pragma unroll
            for (int q = 0; q < 4; ++q) pk[q] = cvtpk(f[q * 2], f[q * 2 + 1]);
            *(uint4*)(As + tbn * 4096 + awoff) = make_uint4(pk[0], pk[1], pk[2], pk[3]);
        }
        __syncthreads();
    }

    // ---- epilogue: bias + tanh, NCHW float4 stores ----
    #pragma unroll
    for (int n = 0; n < 2; ++n) {
        int o = og * 32 + n * 16 + r0;
        float bia = b_conv[o];
        #pragma unroll
        for (int m = 0; m < 2; ++m) {
            int pxo = hw0 + m * 16 + ((lane >> 4) << 2);
            float4 v;
            v.x = fast_tanh(acc[m][n][0] + bia);
            v.y = fast_tanh(acc[m][n][1] + bia);
            v.z = fast_tanh(acc[m][n][2] + bia);
            v.w = fast_tanh(acc[m][n][3] + bia);
            *(float4*)(out + ((size_t)(b * OO + o)) * HWH + pxo) = v;
        }
    }
}

extern "C" void kernel_launch(void* const* d_in, const int* in_sizes, int n_in,
                              void* d_out, int out_size, void* d_ws, size_t ws_size,
                              hipStream_t stream) {
    const float* x      = (const float*)d_in[0];
    const float* w_off  = (const float*)d_in[1];
    const float* b_off  = (const float*)d_in[2];
    const float* w_conv = (const float*)d_in[3];
    const float* b_conv = (const float*)d_in[4];
    const float* fc1    = (const float*)d_in[5];
    const float* fc2    = (const float*)d_in[6];
    float* out = (float*)d_out;
    float* ws  = (float*)d_ws;

    float* y    = ws;                                  // 2048
    float* s    = y + 2048;                            // 2048
    float* offs = s + 2048;                            // 451584
    unsigned short* x_t = (unsigned short*)(offs + 451584);    // 6422528 shorts
    unsigned short* wbo = x_t + 6422528;                       // 73728 shorts (pre-swizzled tiles)
    unsigned short* wbf = wbo + 73728;                         // 589824 shorts (frag layout)
    int4*   ci = (int4*)(wbf + 589824);                        // 225792 int4
    float4* cf = (float4*)(ci + 225792);                       // 225792 float4

    se_mean<<<BB * CC, 256, 0, stream>>>(x, y);
    se_fc<<<1, 256, 0, stream>>>(y, fc1, fc2, s);
    prep_wcf<<<288, 256, 0, stream>>>(w_conv, wbf);
    prep_wo<<<36, 256, 0, stream>>>(w_off, wbo);
    prep_xt<<<BB * 49 * 4, 256, 0, stream>>>(x, s, x_t);
    offset_mfma<<<BB * 98, 256, 0, stream>>>(x_t, wbo, b_off, offs);
    coords_prep<<<882, 256, 0, stream>>>(offs, ci, cf);
    deform_mfma<<<BB * 98, 512, 0, stream>>>(x_t, ci, cf, wbf, b_conv, out);
}